// Round 13
// baseline (250.514 us; speedup 1.0000x reference)
//
#include <hip/hip_runtime.h>
#include <hip/hip_bf16.h>

// Problem constants
constexpr int B_ = 512;
constexpr int T_ = 128;
constexpr int D_ = 768;
constexpr int CD_ = 192;
constexpr int SD_ = 128;
constexpr int P_ = 128;
constexpr int FEAT_ = 321;   // CD + SD + 1
constexpr float LN_EPS_ = 1e-5f;

// ws floats: rep [B][1536] | dn16 | dot | part | projp [chunk][2][128][128] f32
constexpr size_t REP_SZ   = (size_t)B_ * 2 * D_;     // 786432
constexpr size_t DN16_FLT = (size_t)P_ * D_ / 2;     // 49152
constexpr size_t FIXED_FLT = REP_SZ + DN16_FLT + B_ + CD_;
constexpr size_t PROJ_PER_B = 2ull * 128 * 128 * 4;  // bytes per batch

typedef __attribute__((ext_vector_type(8))) short short8;   // 8 bf16
typedef __attribute__((ext_vector_type(4))) float f32x4;
typedef unsigned long long ull_t;

__device__ __forceinline__ unsigned short f2bf(float x) {
    unsigned u = __float_as_uint(x);
    return (unsigned short)((u + 0x7FFFu + ((u >> 16) & 1u)) >> 16);
}
__device__ __forceinline__ float bf2f(unsigned short h) {
    return __uint_as_float((unsigned)h << 16);
}

// ---------------------------------------------------------------------------
// Kernel 1: dirs_n = dirs / ||dirs||, bf16, row-major
// ---------------------------------------------------------------------------
__global__ __launch_bounds__(256) void k_dirs(const float* __restrict__ dirs,
                                              unsigned short* __restrict__ dn16) {
    int p = blockIdx.x;
    int tid = threadIdx.x;
    float s = 0.f;
    for (int d = tid; d < D_; d += 256) {
        float v = dirs[(size_t)p * D_ + d];
        s = fmaf(v, v, s);
    }
    __shared__ float red[256];
    red[tid] = s;
    __syncthreads();
    for (int off = 128; off > 0; off >>= 1) {
        if (tid < off) red[tid] += red[tid + off];
        __syncthreads();
    }
    float inv = 1.0f / sqrtf(red[0]);
    for (int d = tid; d < D_; d += 256) {
        dn16[(size_t)p * D_ + d] = f2bf(dirs[(size_t)p * D_ + d] * inv);
    }
}

// ---------------------------------------------------------------------------
// Kernel 2: k_gemm — K-split 128x128 MFMA GEMM, grid (B,2): block (b,kh) does
// K in [kh*384, kh*384+384). r6-winner pipeline: depth-2 reg prefetch, dbuf
// LDS, 2 raw barriers/iter, compiler-tracked waits. Fused rep (gather
// mask-MFMA). Output: fp32 proj partial to global; rep (cls+diff) ranges.
// 512 threads, LDS ~33 KB -> 4 blocks/CU; 1024 blocks -> full wave coverage.
// ---------------------------------------------------------------------------
constexpr int NITH_ = 12;           // 384 / 32

__global__ __launch_bounds__(512) void k_gemm(const float* __restrict__ H,
                                              const int* __restrict__ tt,
                                              const int* __restrict__ attn,
                                              const unsigned short* __restrict__ dn16,
                                              float* __restrict__ rep,
                                              float* __restrict__ projp,
                                              int bOff) {
    const int b = bOff + blockIdx.x;
    const int kh = blockIdx.y;
    const int kbase = kh * 384;
    const int tid = threadIdx.x;
    const int lane = tid & 63;
    const int w = tid >> 6;           // wave 0..7
    const int wr = w >> 2;            // t-row half
    const int wc = w & 3;             // p-col quarter
    const int fr = lane & 15;
    const int kg = lane >> 4;

    __shared__ __align__(16) unsigned short stage[2 * 8192];  // 32 KB (A 4096 + B 4096 per buf)
    __shared__ unsigned short mask16[256];
    __shared__ ull_t xch[4];

    // --- staging geometry; issue depth-2 prefetch ASAP ---
    const float* Hb = H + (size_t)b * T_ * D_;
    const int srow = tid >> 2;                 // 0..127
    const int scp  = tid & 3;                  // phys 16B chunk (8 u16)
    const int sclog = scp ^ ((srow >> 1) & 3); // logical chunk (source pre-swizzle)
    const float* gA = Hb + (size_t)srow * D_ + kbase + sclog * 8;
    const unsigned short* gB = dn16 + (size_t)srow * D_ + kbase + sclog * 8;
    const int dOffA = srow * 32 + scp * 8;
    const int dOffB = 4096 + dOffA;

    float4 a0A = *reinterpret_cast<const float4*>(gA);
    float4 a1A = *reinterpret_cast<const float4*>(gA + 4);
    short8 bvA = *reinterpret_cast<const short8*>(gB);
    float4 a0B = *reinterpret_cast<const float4*>(gA + 32);
    float4 a1B = *reinterpret_cast<const float4*>(gA + 36);
    short8 bvB = *reinterpret_cast<const short8*>(gB + 32);

    // --- phase 0: masks via ballot (counts) + bf16 mask rows ---
    const int myt = 64 * wr + lane;
    int vt = tt[b * T_ + myt];
    int va = attn[b * T_ + myt];
    bool m0 = (vt == 0) && (va == 1);
    bool m1 = (vt == 1) && (va == 1);
    ull_t bal0 = __ballot(m0);
    ull_t bal1 = __ballot(m1);
    if (lane == 0 && (w == 0 || w == 4)) {
        xch[wr * 2] = bal0;
        xch[wr * 2 + 1] = bal1;
    }
    if (tid < 128) {
        int t2 = tt[b * T_ + tid];
        int a2 = attn[b * T_ + tid];
        mask16[tid]       = (t2 == 0 && a2 == 1) ? 0x3F80u : 0u;
        mask16[128 + tid] = (t2 == 1 && a2 == 1) ? 0x3F80u : 0u;
    }
    __syncthreads();
    const int n0 = __popcll(xch[0]) + __popcll(xch[2]);
    const int n1 = __popcll(xch[1]) + __popcll(xch[3]);
    const float inv0 = 1.f / (float)max(n0, 1);
    const float inv1 = 1.f / (float)max(n1, 1);

    // --- frag addresses ---
    const int baseA = (64 * wr + fr) * 32 + (kg ^ ((fr >> 1) & 3)) * 8;
    const int baseB = 4096 + (32 * wc + fr) * 32 + (kg ^ ((fr >> 1) & 3)) * 8;
    const int grp = w & 1;            // rep d-half for duty waves
    const int dl = grp * 16 + fr;
    const int dch = dl >> 3, dsub = dl & 7;
    float* repb = rep + (size_t)b * 2 * D_;

    f32x4 acc[4][2];
#pragma unroll
    for (int m = 0; m < 4; ++m)
#pragma unroll
        for (int n = 0; n < 2; ++n) acc[m][n] = (f32x4){0.f, 0.f, 0.f, 0.f};

    auto body = [&](int it, unsigned short* sb, float4& pa0, float4& pa1, short8& pbv) {
        // convert + stage current tile (compiler waits the pa/pbv vmcnt deps)
        short8 wv;
        wv[0] = (short)f2bf(pa0.x); wv[1] = (short)f2bf(pa0.y);
        wv[2] = (short)f2bf(pa0.z); wv[3] = (short)f2bf(pa0.w);
        wv[4] = (short)f2bf(pa1.x); wv[5] = (short)f2bf(pa1.y);
        wv[6] = (short)f2bf(pa1.z); wv[7] = (short)f2bf(pa1.w);
        *reinterpret_cast<short8*>(sb + dOffA) = wv;
        *reinterpret_cast<short8*>(sb + dOffB) = pbv;
        if (srow == 0) {   // cls = H[b,0,:] exact fp32 (this K-half's range)
            float* cd = repb + kbase + it * 32 + sclog * 8;
            *reinterpret_cast<float4*>(cd)     = pa0;
            *reinterpret_cast<float4*>(cd + 4) = pa1;
        }
        if (it + 2 < NITH_) {   // depth-2 prefetch (in flight across barriers+MFMA)
            int k = (it + 2) * 32;
            pa0 = *reinterpret_cast<const float4*>(gA + k);
            pa1 = *reinterpret_cast<const float4*>(gA + k + 4);
            pbv = *reinterpret_cast<const short8*>(gB + k);
        }
        asm volatile("s_waitcnt lgkmcnt(0)" ::: "memory");
        __builtin_amdgcn_s_barrier();
        asm volatile("" ::: "memory");

        short8 af[4], bf_[2];
#pragma unroll
        for (int m = 0; m < 4; ++m)
            af[m] = *reinterpret_cast<const short8*>(sb + baseA + 512 * m);
#pragma unroll
        for (int n = 0; n < 2; ++n)
            bf_[n] = *reinterpret_cast<const short8*>(sb + baseB + 512 * n);
#pragma unroll
        for (int m = 0; m < 4; ++m)
#pragma unroll
            for (int n = 0; n < 2; ++n)
                acc[m][n] = __builtin_amdgcn_mfma_f32_16x16x32_bf16(af[m], bf_[n], acc[m][n], 0, 0, 0);

        // fused rep: duty = 2 waves per parity; contraction over t via mask-MFMA
        bool duty = ((it & 1) == 0) ? (w == 0 || w == 1) : (w == 4 || w == 5);
        if (duty) {
            f32x4 ar = (f32x4){0.f, 0.f, 0.f, 0.f};
#pragma unroll
            for (int tc = 0; tc < 4; ++tc) {
                int tbase = tc * 32 + kg * 8;
                short8 am = {0, 0, 0, 0, 0, 0, 0, 0};
                if (fr < 2) am = *reinterpret_cast<const short8*>(&mask16[fr * 128 + tbase]);
                short8 bm;
#pragma unroll
                for (int j = 0; j < 8; ++j) {
                    int t = tbase + j;
                    bm[j] = (short)sb[t * 32 + (dch ^ ((t >> 1) & 3)) * 8 + dsub];
                }
                ar = __builtin_amdgcn_mfma_f32_16x16x32_bf16(am, bm, ar, 0, 0, 0);
            }
            if (lane < 16)
                repb[D_ + kbase + it * 32 + grp * 16 + lane] = ar[0] * inv0 - ar[1] * inv1;
        }
        asm volatile("" ::: "memory");
        __builtin_amdgcn_s_barrier();
        asm volatile("" ::: "memory");
    };

    for (int mi = 0; mi < NITH_ / 2; ++mi) {
        body(2 * mi,     stage,        a0A, a1A, bvA);
        body(2 * mi + 1, stage + 8192, a0B, a1B, bvB);
    }

    // --- epilogue: store fp32 proj partial (raw layout) to global ---
    float* pg = projp + ((size_t)blockIdx.x * 2 + kh) * 16384;
#pragma unroll
    for (int m = 0; m < 4; ++m) {
#pragma unroll
        for (int n = 0; n < 2; ++n) {
            int col = 32 * wc + 16 * n + fr;
#pragma unroll
            for (int r = 0; r < 4; ++r) {
                int row = 64 * wr + 16 * m + kg * 4 + r;
                pg[row * 128 + col] = acc[m][n][r];
            }
        }
    }
}

// ---------------------------------------------------------------------------
// Kernel 3: k_rank — sum 2 fp32 partials, permute+sortable-u16, key-rank,
// paired diff. 512 threads, one block per batch.
// ---------------------------------------------------------------------------
__global__ __launch_bounds__(512) void k_rank(const int* __restrict__ tt,
                                              const int* __restrict__ attn,
                                              const float* __restrict__ projp,
                                              float* __restrict__ d_ot,
                                              int bOff) {
    const int b = bOff + blockIdx.x;
    const int tid = threadIdx.x;
    const int lane = tid & 63;
    const int w = tid >> 6;
    const int wr = w >> 2;

    __shared__ __align__(16) unsigned short proj16[16384];  // 32 KB
    __shared__ unsigned char xb[8192];
    __shared__ unsigned char yb[8192];
    __shared__ float dred[512];
    __shared__ ull_t xch[4];
    __shared__ unsigned char pos_s[T_];

    // --- ballot, counts, pos map (r11-proven pattern) ---
    const int myt = 64 * wr + lane;
    int vt = tt[b * T_ + myt];
    int va = attn[b * T_ + myt];
    bool m0 = (vt == 0) && (va == 1);
    bool m1 = (vt == 1) && (va == 1);
    ull_t bal0 = __ballot(m0);
    ull_t bal1 = __ballot(m1);
    if (lane == 0 && (w == 0 || w == 4)) {
        xch[wr * 2] = bal0;
        xch[wr * 2 + 1] = bal1;
    }
    __syncthreads();
    const ull_t lo0 = xch[0], lo1 = xch[1], hi0 = xch[2], hi1 = xch[3];
    const int n0 = __popcll(lo0) + __popcll(hi0);
    const int n1 = __popcll(lo1) + __popcll(hi1);
    const int ntot = n0 + n1;
    const int mmv = min(n0, n1);
    ull_t below = (1ull << lane) - 1ull;
    int mypos = 0xFF;
    if (m0) mypos = (wr ? __popcll(lo0) : 0) + __popcll((wr ? hi0 : lo0) & below);
    else if (m1) mypos = n0 + (wr ? __popcll(lo1) : 0) + __popcll((wr ? hi1 : lo1) & below);
    if (w == 0 || w == 4) pos_s[myt] = (unsigned char)mypos;
    __syncthreads();

    // --- staging: sum halves, convert, permuted write ---
    const float* pg0 = projp + (size_t)blockIdx.x * 2 * 16384;
    const float* pg1 = pg0 + 16384;
    const int t = tid >> 2;
    const int cgb = (tid & 3) * 32;
    const int pp = pos_s[t];
    if (pp != 0xFF) {
#pragma unroll
        for (int j4 = 0; j4 < 8; ++j4) {
            float4 u = *reinterpret_cast<const float4*>(pg0 + t * 128 + cgb + 4 * j4);
            float4 v = *reinterpret_cast<const float4*>(pg1 + t * 128 + cgb + 4 * j4);
            float sv[4] = {u.x + v.x, u.y + v.y, u.z + v.z, u.w + v.w};
            ushort4 o;
            unsigned bb;
            bb = f2bf(sv[0]); o.x = (unsigned short)(bb ^ ((bb >> 15) ? 0xFFFFu : 0x8000u));
            bb = f2bf(sv[1]); o.y = (unsigned short)(bb ^ ((bb >> 15) ? 0xFFFFu : 0x8000u));
            bb = f2bf(sv[2]); o.z = (unsigned short)(bb ^ ((bb >> 15) ? 0xFFFFu : 0x8000u));
            bb = f2bf(sv[3]); o.w = (unsigned short)(bb ^ ((bb >> 15) ? 0xFFFFu : 0x8000u));
            *reinterpret_cast<ushort4*>(&proj16[pp * 128 + cgb + 4 * j4]) = o;
        }
    }
    __syncthreads();

    // --- phase 2: ranking via sortable-u32 keys, single pass x 32 keys ---
    const int c = tid & 127;
    const int q = tid >> 7;
    const int pbase = q * 32;
    {
        unsigned kv[32];
        int cnt[32];
#pragma unroll
        for (int ii = 0; ii < 32; ++ii) {
            int p = pbase + ii;
            unsigned key = 0xFFFFFFFFu;
            if (p < ntot) {
                unsigned su = proj16[p * 128 + c];
                key = ((unsigned)(p >= n0) << 31) | (su << 8) | (unsigned)p;
            }
            kv[ii] = key;
            cnt[ii] = 0;
        }
        int lo, hi;
        if (pbase + 32 <= n0) { lo = 0;  hi = n0;   }
        else if (pbase >= n0) { lo = n0; hi = ntot; }
        else                  { lo = 0;  hi = ntot; }
        for (int j = lo; j < hi; ++j) {
            unsigned su = proj16[j * 128 + c];
            unsigned kw = ((unsigned)(j >= n0) << 31) | (su << 8) | (unsigned)j;
#pragma unroll
            for (int ii = 0; ii < 32; ++ii) cnt[ii] += (kw < kv[ii]) ? 1 : 0;
        }
#pragma unroll
        for (int ii = 0; ii < 32; ++ii) {
            int p = pbase + ii;
            if (p < ntot) {
                int rank = cnt[ii] - ((p >= n0 && lo == 0) ? n0 : 0);
                if (rank < mmv) {
                    unsigned char* buf = (p >= n0) ? yb : xb;
                    buf[rank * 128 + c] = (unsigned char)p;
                }
            }
        }
    }
    __syncthreads();

    // --- phase 3: paired diff per column, max over columns ---
    float part = 0.f;
    for (int r = q; r < mmv; r += 4) {
        unsigned sx = proj16[(int)xb[r * 128 + c] * 128 + c];
        unsigned sy = proj16[(int)yb[r * 128 + c] * 128 + c];
        unsigned bx = sx ^ ((sx >> 15) ? 0x8000u : 0xFFFFu);
        unsigned byv = sy ^ ((sy >> 15) ? 0x8000u : 0xFFFFu);
        part += fabsf(bf2f((unsigned short)bx) - bf2f((unsigned short)byv));
    }
    dred[tid] = part;
    __syncthreads();
    if (tid < 128) {
        float invm = 1.f / (float)max(mmv, 1);
        dred[tid] = (dred[tid] + dred[tid + 128] + dred[tid + 256] + dred[tid + 384]) * invm;
    }
    __syncthreads();
    if (tid < 64) {
        float m = fmaxf(dred[tid], dred[tid + 64]);
#pragma unroll
        for (int off = 32; off > 0; off >>= 1) m = fmaxf(m, __shfl_xor(m, off));
        if (tid == 0) d_ot[b] = m;
    }
}

// ---------------------------------------------------------------------------
// Kernel 4: head — C/S GEMV + gate + LayerNorm + logits. 2 batches/block.
// ---------------------------------------------------------------------------
__global__ __launch_bounds__(320) void k_head(const float* __restrict__ rep,
                                              const float* __restrict__ Wc,
                                              const float* __restrict__ bc,
                                              const float* __restrict__ Ws,
                                              const float* __restrict__ bs,
                                              const float* __restrict__ gate,
                                              const float* __restrict__ lng,
                                              const float* __restrict__ lnb,
                                              const float* __restrict__ Wcls,
                                              const float* __restrict__ bcls,
                                              const float* __restrict__ d_ot,
                                              float* __restrict__ out) {
    int b0 = blockIdx.x * 2;
    int tid = threadIdx.x;
    __shared__ __align__(16) float repS[2 * 1536];
    __shared__ float featS[2 * FEAT_];

    const float4* repg = reinterpret_cast<const float4*>(rep + (size_t)b0 * 1536);
    float4* repl = reinterpret_cast<float4*>(repS);
    for (int i = tid; i < 768; i += 320) repl[i] = repg[i];
    __syncthreads();

    float g = 1.f / (1.f + expf(-gate[0]));

    {
        int o = tid;  // 0..319
        bool isC = o < CD_;
        const float* wptr = isC ? (Wc + (size_t)o * 1536) : (Ws + (size_t)(o - CD_) * 1536);
        float bias = isC ? bc[o] : bs[o - CD_];
        float scale = isC ? (1.f - g) : g;
        const float4* w4 = reinterpret_cast<const float4*>(wptr);
        float a0 = 0.f, a1 = 0.f;
        for (int k4 = 0; k4 < 384; ++k4) {
            float4 wv = w4[k4];
            float4 r0 = repl[k4];
            float4 r1 = repl[384 + k4];
            a0 += fmaf(wv.x, r0.x, fmaf(wv.y, r0.y, fmaf(wv.z, r0.z, wv.w * r0.w)));
            a1 += fmaf(wv.x, r1.x, fmaf(wv.y, r1.y, fmaf(wv.z, r1.z, wv.w * r1.w)));
        }
        featS[0 * FEAT_ + o] = (a0 + bias) * scale;
        featS[1 * FEAT_ + o] = (a1 + bias) * scale;
    }
    if (tid < 2) featS[tid * FEAT_ + 320] = d_ot[b0 + tid];
    __syncthreads();

    int w = tid >> 6, lane = tid & 63;
    if (w < 2) {
        const float* f = featS + w * FEAT_;
        float s = 0.f, s2 = 0.f;
        for (int i = lane; i < FEAT_; i += 64) {
            float v = f[i];
            s += v;
            s2 = fmaf(v, v, s2);
        }
#pragma unroll
        for (int off = 32; off > 0; off >>= 1) {
            s += __shfl_xor(s, off);
            s2 += __shfl_xor(s2, off);
        }
        float mu = s * (1.f / (float)FEAT_);
        float var = fmaxf(s2 * (1.f / (float)FEAT_) - mu * mu, 0.f);
        float rstd = 1.0f / sqrtf(var + LN_EPS_);
        float l0 = 0.f, l1 = 0.f;
        for (int i = lane; i < FEAT_; i += 64) {
            float nv = (f[i] - mu) * rstd * lng[i] + lnb[i];
            l0 = fmaf(nv, Wcls[i], l0);
            l1 = fmaf(nv, Wcls[FEAT_ + i], l1);
        }
#pragma unroll
        for (int off = 32; off > 0; off >>= 1) {
            l0 += __shfl_xor(l0, off);
            l1 += __shfl_xor(l1, off);
        }
        if (lane == 0) {
            out[(size_t)(b0 + w) * 2 + 0] = l0 + bcls[0];
            out[(size_t)(b0 + w) * 2 + 1] = l1 + bcls[1];
        }
    }
}

// ---------------------------------------------------------------------------
// Kernel 5/6: ortho = mean((Wc @ Ws^T)^2)
// ---------------------------------------------------------------------------
__global__ __launch_bounds__(256) void k_ortho(const float* __restrict__ Wc,
                                               const float* __restrict__ Ws,
                                               float* __restrict__ part) {
    int i = blockIdx.x;
    int tid = threadIdx.x;
    __shared__ float wrow[1536];
    __shared__ float tmp[256];
    for (int k = tid; k < 1536; k += 256) wrow[k] = Wc[(size_t)i * 1536 + k];
    __syncthreads();
    int j = tid & 127, h = tid >> 7;
    const float* wsr = Ws + (size_t)j * 1536 + h * 768;
    const float* wr = wrow + h * 768;
    float s = 0.f;
    for (int k = 0; k < 768; ++k) s = fmaf(wr[k], wsr[k], s);
    tmp[tid] = s;
    __syncthreads();
    if (tid < 128) {
        float d = tmp[tid] + tmp[tid + 128];
        tmp[tid] = d * d;
    }
    __syncthreads();
    for (int off = 64; off > 0; off >>= 1) {
        if (tid < off) tmp[tid] += tmp[tid + off];
        __syncthreads();
    }
    if (tid == 0) part[i] = tmp[0];
}

__global__ __launch_bounds__(256) void k_ortho2(const float* __restrict__ part,
                                                float* __restrict__ out) {
    int tid = threadIdx.x;
    __shared__ float red[256];
    red[tid] = (tid < CD_) ? part[tid] : 0.f;
    __syncthreads();
    for (int off = 128; off > 0; off >>= 1) {
        if (tid < off) red[tid] += red[tid + off];
        __syncthreads();
    }
    if (tid == 0) out[(size_t)B_ * 2] = red[0] / (float)(CD_ * SD_);
}

// ---------------------------------------------------------------------------
extern "C" void kernel_launch(void* const* d_in, const int* in_sizes, int n_in,
                              void* d_out, int out_size, void* d_ws, size_t ws_size,
                              hipStream_t stream) {
    const float* H    = (const float*)d_in[0];
    const int*   tt   = (const int*)d_in[1];
    const int*   attn = (const int*)d_in[2];
    const float* Wc   = (const float*)d_in[3];
    const float* bc   = (const float*)d_in[4];
    const float* Ws   = (const float*)d_in[5];
    const float* bs   = (const float*)d_in[6];
    const float* gate = (const float*)d_in[7];
    const float* lng  = (const float*)d_in[8];
    const float* lnb  = (const float*)d_in[9];
    const float* Wcls = (const float*)d_in[10];
    const float* bcls = (const float*)d_in[11];
    const float* dirs = (const float*)d_in[12];

    float* ws    = (float*)d_ws;
    float* rep   = ws;                                      // [B][1536] fp32
    unsigned short* dn16 = (unsigned short*)(ws + REP_SZ);  // [P][D] bf16 row-major
    float* dot   = ws + REP_SZ + DN16_FLT;                  // [B]
    float* part  = dot + B_;                                // [CD]
    float* projp = ws + FIXED_FLT;                          // [chunk][2][128][128] f32
    float* out   = (float*)d_out;

    // batch chunk size limited by workspace
    size_t availB = (ws_size > FIXED_FLT * 4) ? (ws_size - FIXED_FLT * 4) : 0;
    int maxB = (int)(availB / PROJ_PER_B);
    int chunk = B_;
    while (chunk > maxB && chunk > 1) chunk >>= 1;
    if (chunk > maxB) chunk = 1;

    k_dirs<<<P_, 256, 0, stream>>>(dirs, dn16);
    for (int c = 0; c < B_; c += chunk) {
        int nb = min(chunk, B_ - c);
        k_gemm<<<dim3(nb, 2), 512, 0, stream>>>(H, tt, attn, dn16, rep, projp, c);
        k_rank<<<nb, 512, 0, stream>>>(tt, attn, projp, dot, c);
    }
    k_head<<<B_ / 2, 320, 0, stream>>>(rep, Wc, bc, Ws, bs, gate, lng, lnb, Wcls, bcls, dot, out);
    k_ortho<<<CD_, 256, 0, stream>>>(Wc, Ws, part);
    k_ortho2<<<1, 256, 0, stream>>>(part, out);
}

// Round 14
// 187.608 us; speedup vs baseline: 1.3353x; 1.3353x over previous
//
#include <hip/hip_runtime.h>
#include <hip/hip_bf16.h>

// Problem constants
constexpr int B_ = 512;
constexpr int T_ = 128;
constexpr int D_ = 768;
constexpr int CD_ = 192;
constexpr int SD_ = 128;
constexpr int P_ = 128;
constexpr int FEAT_ = 321;   // CD + SD + 1
constexpr float LN_EPS_ = 1e-5f;

constexpr size_t REP_SZ   = (size_t)B_ * 2 * D_;     // 786432 floats
constexpr size_t DN16_FLT = (size_t)P_ * D_ / 2;     // 49152 floats

typedef __attribute__((ext_vector_type(8))) short short8;   // 8 bf16 (4 VGPRs)
typedef __attribute__((ext_vector_type(4))) float f32x4;
typedef unsigned long long ull_t;

__device__ __forceinline__ unsigned short f2bf(float x) {
    unsigned u = __float_as_uint(x);
    return (unsigned short)((u + 0x7FFFu + ((u >> 16) & 1u)) >> 16);
}
__device__ __forceinline__ float bf2f(unsigned short h) {
    return __uint_as_float((unsigned)h << 16);
}

// ---------------------------------------------------------------------------
// Kernel 1: dirs_n = dirs / ||dirs||, bf16, row-major
// ---------------------------------------------------------------------------
__global__ __launch_bounds__(256) void k_dirs(const float* __restrict__ dirs,
                                              unsigned short* __restrict__ dn16) {
    int p = blockIdx.x;
    int tid = threadIdx.x;
    float s = 0.f;
    for (int d = tid; d < D_; d += 256) {
        float v = dirs[(size_t)p * D_ + d];
        s = fmaf(v, v, s);
    }
    __shared__ float red[256];
    red[tid] = s;
    __syncthreads();
    for (int off = 128; off > 0; off >>= 1) {
        if (tid < off) red[tid] += red[tid + off];
        __syncthreads();
    }
    float inv = 1.0f / sqrtf(red[0]);
    for (int d = tid; d < D_; d += 256) {
        dn16[(size_t)p * D_ + d] = f2bf(dirs[(size_t)p * D_ + d] * inv);
    }
}

// ---------------------------------------------------------------------------
// Kernel 2: r6-winner monolithic 128x128 MFMA GEMM (depth-2 reg prefetch,
// dbuf LDS, 2 raw barriers/iter, compiler-tracked waits) + fused rep
// (gather mask-MFMA, r13-proven) + key-rank + paired diff.
// proj16 OVERLAYS the stage buffer -> LDS 51712 B -> 3 blocks/CU.
// 512 threads, one block per batch.
// ---------------------------------------------------------------------------
constexpr int NIT_ = 24;            // 768 / 32
constexpr int BUF_U16_ = 8192;      // A 4096 + B 4096 u16 per buffer (16 KB)

__global__ __launch_bounds__(512) void k_projsort(const float* __restrict__ H,
                                                  const int* __restrict__ tt,
                                                  const int* __restrict__ attn,
                                                  const unsigned short* __restrict__ dn16,
                                                  float* __restrict__ rep,
                                                  float* __restrict__ d_ot) {
    const int b = blockIdx.x;
    const int tid = threadIdx.x;
    const int lane = tid & 63;
    const int w = tid >> 6;           // wave 0..7
    const int wr = w >> 2;            // t-row half
    const int wc = w & 3;             // p-col quarter
    const int fr = lane & 15;
    const int kg = lane >> 4;

    __shared__ __align__(16) unsigned short stage[2 * BUF_U16_];  // 32 KB; proj16 overlay post-GEMM
    __shared__ unsigned char xb[8192];                            // [64][128]
    __shared__ unsigned char yb[8192];
    __shared__ float dred[512];                                   // + ballot exchange overlay
    __shared__ unsigned short mask16[256];                        // bf16 mask rows
    unsigned short* proj16 = stage;
    ull_t* xch = (ull_t*)dred;

    // --- staging geometry; issue depth-2 prefetch ASAP ---
    const float* Hb = H + (size_t)b * T_ * D_;
    const int srow = tid >> 2;                 // 0..127
    const int scp  = tid & 3;                  // phys 16B chunk (8 u16)
    const int sclog = scp ^ ((srow >> 1) & 3); // logical chunk (source pre-swizzle)
    const float* gA = Hb + (size_t)srow * D_ + sclog * 8;
    const unsigned short* gB = dn16 + (size_t)srow * D_ + sclog * 8;
    const int dOffA = srow * 32 + scp * 8;
    const int dOffB = 4096 + dOffA;

    float4 a0A = *reinterpret_cast<const float4*>(gA);
    float4 a1A = *reinterpret_cast<const float4*>(gA + 4);
    short8 bvA = *reinterpret_cast<const short8*>(gB);
    float4 a0B = *reinterpret_cast<const float4*>(gA + 32);
    float4 a1B = *reinterpret_cast<const float4*>(gA + 36);
    short8 bvB = *reinterpret_cast<const short8*>(gB + 32);

    // --- phase 0: masks via ballot, counts, per-row pos (regs), mask rows ---
    const int myt = 64 * wr + lane;
    int vt = tt[b * T_ + myt];
    int va = attn[b * T_ + myt];
    bool m0 = (vt == 0) && (va == 1);
    bool m1 = (vt == 1) && (va == 1);
    ull_t bal0 = __ballot(m0);
    ull_t bal1 = __ballot(m1);
    if (lane == 0 && (w == 0 || w == 4)) {
        xch[wr * 2] = bal0;
        xch[wr * 2 + 1] = bal1;
    }
    if (tid < 128) {
        int t2 = tt[b * T_ + tid];
        int a2 = attn[b * T_ + tid];
        mask16[tid]       = (t2 == 0 && a2 == 1) ? 0x3F80u : 0u;
        mask16[128 + tid] = (t2 == 1 && a2 == 1) ? 0x3F80u : 0u;
    }
    __syncthreads();
    const ull_t lo0 = xch[0], lo1 = xch[1], hi0 = xch[2], hi1 = xch[3];
    const int n0 = __popcll(lo0) + __popcll(hi0);
    const int n1 = __popcll(lo1) + __popcll(hi1);
    const int ntot = n0 + n1;
    const float inv0 = 1.f / (float)max(n0, 1);
    const float inv1 = 1.f / (float)max(n1, 1);
    ull_t below = (1ull << lane) - 1ull;
    int mypos = 0xFF;
    if (m0) mypos = (wr ? __popcll(lo0) : 0) + __popcll((wr ? hi0 : lo0) & below);
    else if (m1) mypos = n0 + (wr ? __popcll(lo1) : 0) + __popcll((wr ? hi1 : lo1) & below);
    __syncthreads();   // xch consumed before dred reuse; mask16 visible

    // --- phase 1: GEMM (r6 pipeline) + fused rep (gather mask-MFMA) ---
    const int ck = (kg ^ ((fr >> 1) & 3)) * 8;           // swizzled k-chunk
    const int baseA = (64 * wr + fr) * 32 + ck;          // + 512*m
    const int baseB = 4096 + (32 * wc + fr) * 32 + ck;   // + 512*n
    const int grp = w & 1;            // rep d-half for duty waves
    const int dl = grp * 16 + fr;
    const int dch = dl >> 3, dsub = dl & 7;
    float* repb = rep + (size_t)b * 2 * D_;

    f32x4 acc[4][2];
#pragma unroll
    for (int m = 0; m < 4; ++m)
#pragma unroll
        for (int n = 0; n < 2; ++n) acc[m][n] = (f32x4){0.f, 0.f, 0.f, 0.f};

    auto body = [&](int it, unsigned short* sb, float4& pa0, float4& pa1, short8& pbv) {
        // convert + stage current tile (compiler waits the pa/pbv vmcnt deps)
        short8 wv;
        wv[0] = (short)f2bf(pa0.x); wv[1] = (short)f2bf(pa0.y);
        wv[2] = (short)f2bf(pa0.z); wv[3] = (short)f2bf(pa0.w);
        wv[4] = (short)f2bf(pa1.x); wv[5] = (short)f2bf(pa1.y);
        wv[6] = (short)f2bf(pa1.z); wv[7] = (short)f2bf(pa1.w);
        *reinterpret_cast<short8*>(sb + dOffA) = wv;
        *reinterpret_cast<short8*>(sb + dOffB) = pbv;
        if (srow == 0) {   // cls = H[b,0,:] exact fp32
            float* cd = repb + it * 32 + sclog * 8;
            *reinterpret_cast<float4*>(cd)     = pa0;
            *reinterpret_cast<float4*>(cd + 4) = pa1;
        }
        if (it + 2 < NIT_) {   // depth-2 prefetch, in flight across barriers+MFMA
            int k = (it + 2) * 32;
            pa0 = *reinterpret_cast<const float4*>(gA + k);
            pa1 = *reinterpret_cast<const float4*>(gA + k + 4);
            pbv = *reinterpret_cast<const short8*>(gB + k);
        }
        asm volatile("s_waitcnt lgkmcnt(0)" ::: "memory");
        __builtin_amdgcn_s_barrier();
        asm volatile("" ::: "memory");

        short8 af[4], bf_[2];
#pragma unroll
        for (int m = 0; m < 4; ++m)
            af[m] = *reinterpret_cast<const short8*>(sb + baseA + 512 * m);
#pragma unroll
        for (int n = 0; n < 2; ++n)
            bf_[n] = *reinterpret_cast<const short8*>(sb + baseB + 512 * n);
#pragma unroll
        for (int m = 0; m < 4; ++m)
#pragma unroll
            for (int n = 0; n < 2; ++n)
                acc[m][n] = __builtin_amdgcn_mfma_f32_16x16x32_bf16(af[m], bf_[n], acc[m][n], 0, 0, 0);

        // fused rep: duty = 2 waves per parity; contraction over t via mask-MFMA
        bool duty = ((it & 1) == 0) ? (w == 0 || w == 1) : (w == 4 || w == 5);
        if (duty) {
            f32x4 ar = (f32x4){0.f, 0.f, 0.f, 0.f};
#pragma unroll
            for (int tc = 0; tc < 4; ++tc) {
                int tbase = tc * 32 + kg * 8;
                short8 am = {0, 0, 0, 0, 0, 0, 0, 0};
                if (fr < 2) am = *reinterpret_cast<const short8*>(&mask16[fr * 128 + tbase]);
                short8 bm;
#pragma unroll
                for (int j = 0; j < 8; ++j) {
                    int t = tbase + j;
                    bm[j] = (short)sb[t * 32 + (dch ^ ((t >> 1) & 3)) * 8 + dsub];
                }
                ar = __builtin_amdgcn_mfma_f32_16x16x32_bf16(am, bm, ar, 0, 0, 0);
            }
            if (lane < 16)
                repb[D_ + it * 32 + grp * 16 + lane] = ar[0] * inv0 - ar[1] * inv1;
        }
        asm volatile("" ::: "memory");
        __builtin_amdgcn_s_barrier();
        asm volatile("" ::: "memory");
    };

    for (int mi = 0; mi < NIT_ / 2; ++mi) {
        body(2 * mi,     stage,            a0A, a1A, bvA);
        body(2 * mi + 1, stage + BUF_U16_, a0B, a1B, bvB);
    }
    __syncthreads();   // all frag/gather reads drained; stage now dead -> proj16 overlay

    // --- epilogue: proj16[pos[t]][p] as sortable u16 (pos via shfl) ---
#pragma unroll
    for (int m = 0; m < 4; ++m) {
#pragma unroll
        for (int r = 0; r < 4; ++r) {
            int rowlane = 16 * m + kg * 4 + r;
            int pp = __shfl(mypos, rowlane);
            if (pp != 0xFF) {
#pragma unroll
                for (int n = 0; n < 2; ++n) {
                    int col = 32 * wc + 16 * n + fr;
                    unsigned bb = f2bf(acc[m][n][r]);
                    unsigned su = bb ^ ((bb >> 15) ? 0xFFFFu : 0x8000u);
                    proj16[pp * 128 + col] = (unsigned short)su;
                }
            }
        }
    }
    __syncthreads();

    // --- phase 2: ranking via sortable-u32 keys, 2 passes x 16 keys ---
    const int mmv = min(n0, n1);      // <= 64 since n0+n1 <= 128
    const int c = tid & 127;
    const int q = tid >> 7;           // 0..3
#pragma unroll
    for (int pass = 0; pass < 2; ++pass) {
        const int pbase = q * 32 + pass * 16;
        unsigned kv[16];
        int cnt[16];
#pragma unroll
        for (int ii = 0; ii < 16; ++ii) {
            int p = pbase + ii;
            unsigned key = 0xFFFFFFFFu;
            if (p < ntot) {
                unsigned su = proj16[p * 128 + c];
                key = ((unsigned)(p >= n0) << 31) | (su << 8) | (unsigned)p;
            }
            kv[ii] = key;
            cnt[ii] = 0;
        }
        int lo, hi;
        if (pbase + 16 <= n0) { lo = 0;  hi = n0;   }   // pure group-0 chunk
        else if (pbase >= n0) { lo = n0; hi = ntot; }   // pure group-1 chunk
        else                  { lo = 0;  hi = ntot; }   // straddler
        for (int j = lo; j < hi; ++j) {
            unsigned su = proj16[j * 128 + c];
            unsigned kw = ((unsigned)(j >= n0) << 31) | (su << 8) | (unsigned)j;
#pragma unroll
            for (int ii = 0; ii < 16; ++ii) cnt[ii] += (kw < kv[ii]) ? 1 : 0;
        }
#pragma unroll
        for (int ii = 0; ii < 16; ++ii) {
            int p = pbase + ii;
            if (p < ntot) {
                int rank = cnt[ii] - ((p >= n0 && lo == 0) ? n0 : 0);
                if (rank < mmv) {
                    unsigned char* buf = (p >= n0) ? yb : xb;
                    buf[rank * 128 + c] = (unsigned char)p;
                }
            }
        }
    }
    __syncthreads();

    // --- phase 3: paired diff per column, max over columns ---
    float part = 0.f;
    for (int r = q; r < mmv; r += 4) {
        unsigned sx = proj16[(int)xb[r * 128 + c] * 128 + c];
        unsigned sy = proj16[(int)yb[r * 128 + c] * 128 + c];
        unsigned bx = sx ^ ((sx >> 15) ? 0x8000u : 0xFFFFu);
        unsigned byv = sy ^ ((sy >> 15) ? 0x8000u : 0xFFFFu);
        part += fabsf(bf2f((unsigned short)bx) - bf2f((unsigned short)byv));
    }
    dred[tid] = part;
    __syncthreads();
    if (tid < 128) {
        float invm = 1.f / (float)max(mmv, 1);
        dred[tid] = (dred[tid] + dred[tid + 128] + dred[tid + 256] + dred[tid + 384]) * invm;
    }
    __syncthreads();
    if (tid < 64) {
        float m = fmaxf(dred[tid], dred[tid + 64]);
#pragma unroll
        for (int off = 32; off > 0; off >>= 1) m = fmaxf(m, __shfl_xor(m, off));
        if (tid == 0) d_ot[b] = m;    // one block per batch: direct store
    }
}

// ---------------------------------------------------------------------------
// Kernel 3: head — C/S GEMV + gate + LayerNorm + logits.
// 320 threads (1 output each), 4 batches per block, wave-parallel LN.
// ---------------------------------------------------------------------------
__global__ __launch_bounds__(320) void k_head(const float* __restrict__ rep,
                                              const float* __restrict__ Wc,
                                              const float* __restrict__ bc,
                                              const float* __restrict__ Ws,
                                              const float* __restrict__ bs,
                                              const float* __restrict__ gate,
                                              const float* __restrict__ lng,
                                              const float* __restrict__ lnb,
                                              const float* __restrict__ Wcls,
                                              const float* __restrict__ bcls,
                                              const float* __restrict__ d_ot,
                                              float* __restrict__ out) {
    int b0 = blockIdx.x * 4;
    int tid = threadIdx.x;
    __shared__ __align__(16) float repS[4 * 1536];
    __shared__ float featS[4 * FEAT_];

    const float4* repg = reinterpret_cast<const float4*>(rep + (size_t)b0 * 1536);
    float4* repl = reinterpret_cast<float4*>(repS);
    for (int i = tid; i < 1536; i += 320) repl[i] = repg[i];
    __syncthreads();

    float g = 1.f / (1.f + expf(-gate[0]));

    {
        int o = tid;  // 0..319
        bool isC = o < CD_;
        const float* wptr = isC ? (Wc + (size_t)o * 1536) : (Ws + (size_t)(o - CD_) * 1536);
        float bias = isC ? bc[o] : bs[o - CD_];
        float scale = isC ? (1.f - g) : g;
        const float4* w4 = reinterpret_cast<const float4*>(wptr);
        float a0 = 0.f, a1 = 0.f, a2 = 0.f, a3 = 0.f;
        for (int k4 = 0; k4 < 384; ++k4) {
            float4 wv = w4[k4];
            float4 r0 = repl[k4];
            float4 r1 = repl[384 + k4];
            float4 r2 = repl[768 + k4];
            float4 r3 = repl[1152 + k4];
            a0 += fmaf(wv.x, r0.x, fmaf(wv.y, r0.y, fmaf(wv.z, r0.z, wv.w * r0.w)));
            a1 += fmaf(wv.x, r1.x, fmaf(wv.y, r1.y, fmaf(wv.z, r1.z, wv.w * r1.w)));
            a2 += fmaf(wv.x, r2.x, fmaf(wv.y, r2.y, fmaf(wv.z, r2.z, wv.w * r2.w)));
            a3 += fmaf(wv.x, r3.x, fmaf(wv.y, r3.y, fmaf(wv.z, r3.z, wv.w * r3.w)));
        }
        featS[0 * FEAT_ + o] = (a0 + bias) * scale;
        featS[1 * FEAT_ + o] = (a1 + bias) * scale;
        featS[2 * FEAT_ + o] = (a2 + bias) * scale;
        featS[3 * FEAT_ + o] = (a3 + bias) * scale;
    }
    if (tid < 4) featS[tid * FEAT_ + 320] = d_ot[b0 + tid];
    __syncthreads();

    int w = tid >> 6, lane = tid & 63;
    if (w < 4) {   // wave w handles batch b0+w
        const float* f = featS + w * FEAT_;
        float s = 0.f, s2 = 0.f;
        for (int i = lane; i < FEAT_; i += 64) {
            float v = f[i];
            s += v;
            s2 = fmaf(v, v, s2);
        }
#pragma unroll
        for (int off = 32; off > 0; off >>= 1) {
            s += __shfl_xor(s, off);
            s2 += __shfl_xor(s2, off);
        }
        float mu = s * (1.f / (float)FEAT_);
        float var = fmaxf(s2 * (1.f / (float)FEAT_) - mu * mu, 0.f);
        float rstd = 1.0f / sqrtf(var + LN_EPS_);
        float l0 = 0.f, l1 = 0.f;
        for (int i = lane; i < FEAT_; i += 64) {
            float nv = (f[i] - mu) * rstd * lng[i] + lnb[i];
            l0 = fmaf(nv, Wcls[i], l0);
            l1 = fmaf(nv, Wcls[FEAT_ + i], l1);
        }
#pragma unroll
        for (int off = 32; off > 0; off >>= 1) {
            l0 += __shfl_xor(l0, off);
            l1 += __shfl_xor(l1, off);
        }
        if (lane == 0) {
            out[(size_t)(b0 + w) * 2 + 0] = l0 + bcls[0];
            out[(size_t)(b0 + w) * 2 + 1] = l1 + bcls[1];
        }
    }
}

// ---------------------------------------------------------------------------
// Kernel 4/5: ortho = mean((Wc @ Ws^T)^2)
// ---------------------------------------------------------------------------
__global__ __launch_bounds__(256) void k_ortho(const float* __restrict__ Wc,
                                               const float* __restrict__ Ws,
                                               float* __restrict__ part) {
    int i = blockIdx.x;
    int tid = threadIdx.x;
    __shared__ float wrow[1536];
    __shared__ float tmp[256];
    for (int k = tid; k < 1536; k += 256) wrow[k] = Wc[(size_t)i * 1536 + k];
    __syncthreads();
    int j = tid & 127, h = tid >> 7;
    const float* wsr = Ws + (size_t)j * 1536 + h * 768;
    const float* wr = wrow + h * 768;
    float s = 0.f;
    for (int k = 0; k < 768; ++k) s = fmaf(wr[k], wsr[k], s);
    tmp[tid] = s;
    __syncthreads();
    if (tid < 128) {
        float d = tmp[tid] + tmp[tid + 128];
        tmp[tid] = d * d;
    }
    __syncthreads();
    for (int off = 64; off > 0; off >>= 1) {
        if (tid < off) tmp[tid] += tmp[tid + off];
        __syncthreads();
    }
    if (tid == 0) part[i] = tmp[0];
}

__global__ __launch_bounds__(256) void k_ortho2(const float* __restrict__ part,
                                                float* __restrict__ out) {
    int tid = threadIdx.x;
    __shared__ float red[256];
    red[tid] = (tid < CD_) ? part[tid] : 0.f;
    __syncthreads();
    for (int off = 128; off > 0; off >>= 1) {
        if (tid < off) red[tid] += red[tid + off];
        __syncthreads();
    }
    if (tid == 0) out[(size_t)B_ * 2] = red[0] / (float)(CD_ * SD_);
}

// ---------------------------------------------------------------------------
extern "C" void kernel_launch(void* const* d_in, const int* in_sizes, int n_in,
                              void* d_out, int out_size, void* d_ws, size_t ws_size,
                              hipStream_t stream) {
    const float* H    = (const float*)d_in[0];
    const int*   tt   = (const int*)d_in[1];
    const int*   attn = (const int*)d_in[2];
    const float* Wc   = (const float*)d_in[3];
    const float* bc   = (const float*)d_in[4];
    const float* Ws   = (const float*)d_in[5];
    const float* bs   = (const float*)d_in[6];
    const float* gate = (const float*)d_in[7];
    const float* lng  = (const float*)d_in[8];
    const float* lnb  = (const float*)d_in[9];
    const float* Wcls = (const float*)d_in[10];
    const float* bcls = (const float*)d_in[11];
    const float* dirs = (const float*)d_in[12];

    float* ws    = (float*)d_ws;
    float* rep   = ws;                                      // [B][1536] fp32
    unsigned short* dn16 = (unsigned short*)(ws + REP_SZ);  // [P][D] bf16 row-major
    float* dot   = ws + REP_SZ + DN16_FLT;                  // [B]
    float* part  = dot + B_;                                // [CD]
    float* out   = (float*)d_out;

    k_dirs<<<P_, 256, 0, stream>>>(dirs, dn16);
    k_projsort<<<B_, 512, 0, stream>>>(H, tt, attn, dn16, rep, dot);
    k_head<<<B_ / 4, 320, 0, stream>>>(rep, Wc, bc, Ws, bs, gate, lng, lnb, Wcls, bcls, dot, out);
    k_ortho<<<CD_, 256, 0, stream>>>(Wc, Ws, part);
    k_ortho2<<<1, 256, 0, stream>>>(part, out);
}